// Round 6
// baseline (2355.079 us; speedup 1.0000x reference)
//
#include <hip/hip_runtime.h>

#define BB 32
#define TT 1000
#define HH 512
#define G4 2048
#define BTH ((size_t)BB * TT * HH)  // elements per output tensor

typedef short short8 __attribute__((ext_vector_type(8)));
typedef float f32x4 __attribute__((ext_vector_type(4)));

__device__ __forceinline__ unsigned short f2bf(float f) {
    union { float f; unsigned u; } v; v.f = f;
    unsigned r = v.u + 0x7FFF + ((v.u >> 16) & 1);  // RNE; inputs finite
    return (unsigned short)(r >> 16);
}

// ring: u32 words [2 slots][8 groups][32 producers x 64 words]
// word = (bf16(h) << 16) | t  -- self-tagged (R2-proven protocol)
#define RING_WORDS (2 * 8 * 32 * 64)   // 32768 u32 = 128KB (proven within ws_size)

__global__ void lstm_init_ring(unsigned* ring) {
    int i = blockIdx.x * 256 + threadIdx.x;
    __hip_atomic_store(ring + i, 0xFFFFFFFFu, __ATOMIC_RELAXED,
                       __HIP_MEMORY_SCOPE_AGENT);
}

__global__ void __launch_bounds__(256, 1)
lstm_main(const float* __restrict__ wx, const float* __restrict__ u,
          const float* __restrict__ ub, const float* __restrict__ ht0,
          const float* __restrict__ ct0, float* __restrict__ out,
          unsigned* __restrict__ ring)
{
    // double-buffered h tile: one barrier per step
    __shared__ __align__(16) unsigned short lds_h[2][16 * 512];  // 2 x 16KB

    const int tid  = threadIdx.x;
    const int bid  = blockIdx.x;
    const int cg   = bid & 31;   // owns h cols [cg*16, cg*16+16)
    const int qb   = bid >> 5;   // owns batches [qb*4, qb*4+4)
    const int lane = tid & 63;
    const int wv   = tid >> 6;
    const int c    = lane & 15;  // B/D column index within the 16x16 tile
    const int ahi  = lane >> 4;
    const int gate = c >> 2;     // 0=i 1=f 2=g 3=o
    const int jj   = c & 3;
    const int jcol = wv * 4 + jj;   // h col within block's 16 (0..15)

    // ---- zero pad rows 4..15 of BOTH buffers ----
    for (int j = 0; j < 6; ++j) {
        int idx8 = tid + j * 256;             // 1536 x short8 = 2 bufs x 12 rows x 64
        int buf  = idx8 >= 768;
        int r8   = idx8 - buf * 768;
        int r    = 4 + (r8 >> 6);
        int k    = (r8 & 63) * 8;
        short8 z = {0, 0, 0, 0, 0, 0, 0, 0};
        *(short8*)&lds_h[buf][(r * 512 + k) ^ ((r & 7) << 3)] = z;
    }
    // ---- stage initial h (f32 -> bf16) into buf0 ----
    {
        int r = wv, k = lane * 8;
        const float* src = ht0 + (size_t)(qb * 4 + r) * HH + k;
        float4 v0 = *(const float4*)src;
        float4 v1 = *(const float4*)(src + 4);
        union { short8 v8; unsigned short s[8]; } p;
        p.s[0] = f2bf(v0.x); p.s[1] = f2bf(v0.y); p.s[2] = f2bf(v0.z); p.s[3] = f2bf(v0.w);
        p.s[4] = f2bf(v1.x); p.s[5] = f2bf(v1.y); p.s[6] = f2bf(v1.z); p.s[7] = f2bf(v1.w);
        *(short8*)&lds_h[0][(r * 512 + k) ^ ((r & 7) << 3)] = p.v8;
    }

    // ---- preload u fragments: B col c -> u row gate*512 + cg*16 + jcol ----
    short8 breg[16];
    {
        const float* bp = u + (size_t)(gate * HH + cg * 16 + jcol) * HH + ahi * 8;
#pragma unroll
        for (int kk = 0; kk < 16; ++kk) {
            float4 v0 = *(const float4*)(bp + kk * 32);
            float4 v1 = *(const float4*)(bp + kk * 32 + 4);
            union { short8 v8; unsigned short s[8]; } p;
            p.s[0] = f2bf(v0.x); p.s[1] = f2bf(v0.y); p.s[2] = f2bf(v0.z); p.s[3] = f2bf(v0.w);
            p.s[4] = f2bf(v1.x); p.s[5] = f2bf(v1.y); p.s[6] = f2bf(v1.z); p.s[7] = f2bf(v1.w);
            breg[kk] = p.v8;
        }
    }

    const float bias_r = ub[gate * HH + cg * 16 + jcol];

    // c-state: lanes 0..3 of each wave own (all 4 batches) x (col jcol)
    float c_reg[4];
#pragma unroll
    for (int rr = 0; rr < 4; ++rr)
        c_reg[rr] = ct0[(size_t)(qb * 4 + rr) * HH + cg * 16 + jcol];

    // wx bases, one per batch (used by lanes < 16)
    size_t wx0[4];
    size_t ob_act[4], ob_h[4];
#pragma unroll
    for (int rr = 0; rr < 4; ++rr) {
        wx0[rr]    = (size_t)(qb * 4 + rr) * TT * G4 + gate * HH + cg * 16 + jcol;
        ob_act[rr] = (size_t)(2 + gate) * BTH +
                     (size_t)(qb * 4 + rr) * TT * HH + cg * 16 + jcol;
        ob_h[rr]   = (size_t)(qb * 4 + rr) * TT * HH + cg * 16 + jcol;
    }
    float wx_cur[4] = {0, 0, 0, 0}, wx_nxt[4] = {0, 0, 0, 0}, wx_tmp[4] = {0, 0, 0, 0};
    if (lane < 16) {
#pragma unroll
        for (int rr = 0; rr < 4; ++rr) {
            wx_cur[rr] = wx[wx0[rr]];
            wx_nxt[rr] = wx[wx0[rr] + G4];
        }
    }

    // A-frag addressing (row = lane&15 = batch, k = ahi*8 + kk*32)
    const int a_off = c * 512 + ahi * 8;
    const int a_msk = (c & 7) << 3;

    // consumer mapping: thread polls 8 consecutive ring words of one producer
    const int myp = tid >> 3;            // producer 0..31
    const int mw  = (tid & 7) * 8;       // word offset 0..56
    const int mb  = mw >> 4;             // batch row
    const int mj  = mw & 15;             // 0 or 8

    unsigned short hb[4] = {0, 0, 0, 0}; // own h (bf16), carried across iterations

    __syncthreads();

    for (int t = 0; t < TT; ++t) {
        const int cur = t & 1;

        // ---- prefetch wx(t+2) FIRST: in flight across poll + MFMA ----
        if (lane < 16 && t + 2 < TT) {
#pragma unroll
            for (int rr = 0; rr < 4; ++rr)
                wx_tmp[rr] = wx[wx0[rr] + (size_t)(t + 2) * G4];
        }

        // ---- phase 1: stage h_{t-1} into buf[cur] ----
        if (t > 0) {
            if (lane < 4) {   // own columns from registers (computed at t-1)
#pragma unroll
                for (int rr = 0; rr < 4; ++rr)
                    lds_h[cur][(rr * 512 + cg * 16 + jcol) ^ (rr << 3)] = hb[rr];
            }
            if (myp != cg) {  // remote columns via ring poll (R2-proven)
                const unsigned long long* src = (const unsigned long long*)
                    (ring + ((size_t)(cur ^ 1) * 8 + qb) * 2048 + myp * 64 + mw);
                const unsigned tg = (unsigned)(t - 1);
                const unsigned long long want =
                    (unsigned long long)tg | ((unsigned long long)tg << 32);
                const unsigned long long msk = 0x0000FFFF0000FFFFull;
                unsigned long long q0, q1, q2, q3;
                for (;;) {
                    q0 = __hip_atomic_load(src + 0, __ATOMIC_RELAXED, __HIP_MEMORY_SCOPE_AGENT);
                    q1 = __hip_atomic_load(src + 1, __ATOMIC_RELAXED, __HIP_MEMORY_SCOPE_AGENT);
                    q2 = __hip_atomic_load(src + 2, __ATOMIC_RELAXED, __HIP_MEMORY_SCOPE_AGENT);
                    q3 = __hip_atomic_load(src + 3, __ATOMIC_RELAXED, __HIP_MEMORY_SCOPE_AGENT);
                    if (((q0 & msk) == want) & ((q1 & msk) == want) &
                        ((q2 & msk) == want) & ((q3 & msk) == want)) break;
                }
                union { short8 v8; unsigned u[4]; } pv;
                pv.u[0] = ((unsigned)(q0 >> 16) & 0xFFFFu) | ((unsigned)(q0 >> 48) << 16);
                pv.u[1] = ((unsigned)(q1 >> 16) & 0xFFFFu) | ((unsigned)(q1 >> 48) << 16);
                pv.u[2] = ((unsigned)(q2 >> 16) & 0xFFFFu) | ((unsigned)(q2 >> 48) << 16);
                pv.u[3] = ((unsigned)(q3 >> 16) & 0xFFFFu) | ((unsigned)(q3 >> 48) << 16);
                *(short8*)&lds_h[cur][(mb * 512 + myp * 16 + mj) ^ ((mb & 7) << 3)] = pv.v8;
            }
        }
        __syncthreads();   // S1: the only barrier per step

        // ---- phase 2: MFMA over buf[cur], K=512 ----
        f32x4 acc0 = {0.f, 0.f, 0.f, 0.f}, acc1 = {0.f, 0.f, 0.f, 0.f};
#pragma unroll
        for (int kk = 0; kk < 8; ++kk) {
            short8 va0 = *(const short8*)&lds_h[cur][(a_off + kk * 32) ^ a_msk];
            short8 va1 = *(const short8*)&lds_h[cur][(a_off + (kk + 8) * 32) ^ a_msk];
            acc0 = __builtin_amdgcn_mfma_f32_16x16x32_bf16(va0, breg[kk], acc0, 0, 0, 0);
            acc1 = __builtin_amdgcn_mfma_f32_16x16x32_bf16(va1, breg[kk + 8], acc1, 0, 0, 0);
        }
        f32x4 g = acc0 + acc1;   // g[rr] = gates[batch rr][gate, jcol] (lanes 0-15)

        // ---- phase 3: activations, c/h update, publish (no barrier) ----
        if (lane < 16) {
            float act[4];
#pragma unroll
            for (int rr = 0; rr < 4; ++rr) {
                float gv = g[rr] + wx_cur[rr] + bias_r;
                float xs = (gate == 2) ? 2.f * gv : gv;
                float s  = 1.f / (1.f + __expf(-xs));
                act[rr]  = (gate == 2) ? 2.f * s - 1.f : s;  // tanh = 2*sig(2x)-1
            }
            // gather f,g,o for (batch rr, col jcol): lanes 4+jj, 8+jj, 12+jj
            float af[4], ag[4], ao[4];
#pragma unroll
            for (int rr = 0; rr < 4; ++rr) {
                af[rr] = __shfl(act[rr], 4 + jj, 64);
                ag[rr] = __shfl(act[rr], 8 + jj, 64);
                ao[rr] = __shfl(act[rr], 12 + jj, 64);
            }
            if (lane < 4) {   // lanes 0-3 hold the i-gate; do state update
#pragma unroll
                for (int rr = 0; rr < 4; ++rr) {
                    c_reg[rr] = af[rr] * c_reg[rr] + act[rr] * ag[rr];
                    float e2 = __expf(-2.f * c_reg[rr]);
                    float th = 2.f / (1.f + e2) - 1.f;
                    float hn = ao[rr] * th;
                    hb[rr] = f2bf(hn);
                    // publish FIRST (critical inter-block path)
                    unsigned pk = ((unsigned)hb[rr] << 16) | (unsigned)t;
                    __hip_atomic_store(ring + ((size_t)cur * 8 + qb) * 2048 +
                                           cg * 64 + rr * 16 + jcol,
                                       pk, __ATOMIC_RELAXED, __HIP_MEMORY_SCOPE_AGENT);
                    out[ob_h[rr] + (size_t)t * HH] = hn;
                    out[BTH + ob_h[rr] + (size_t)t * HH] = c_reg[rr];
                }
            }
#pragma unroll
            for (int rr = 0; rr < 4; ++rr)
                out[ob_act[rr] + (size_t)t * HH] = act[rr];
        }

        // rotate wx pipeline (wx_tmp load is ~a full iteration old when consumed)
#pragma unroll
        for (int rr = 0; rr < 4; ++rr) {
            wx_cur[rr] = wx_nxt[rr];
            wx_nxt[rr] = wx_tmp[rr];
        }
    }
}

extern "C" void kernel_launch(void* const* d_in, const int* in_sizes, int n_in,
                              void* d_out, int out_size, void* d_ws, size_t ws_size,
                              hipStream_t stream) {
    const float* wx = (const float*)d_in[0];
    const float* u  = (const float*)d_in[1];
    const float* ub = (const float*)d_in[2];
    const float* ht = (const float*)d_in[3];
    const float* ct = (const float*)d_in[4];
    float* out = (float*)d_out;
    unsigned* ring = (unsigned*)d_ws;   // 128KB, proven within ws_size

    lstm_init_ring<<<RING_WORDS / 256, 256, 0, stream>>>(ring);

    void* args[] = {(void*)&wx, (void*)&u, (void*)&ub, (void*)&ht,
                    (void*)&ct, (void*)&out, (void*)&ring};
    hipLaunchCooperativeKernel((void*)lstm_main, dim3(256), dim3(256), args, 0, stream);
}